// Round 8
// baseline (446.154 us; speedup 1.0000x reference)
//
#include <hip/hip_runtime.h>

typedef __bf16 bf16;
typedef __bf16 bf16x4 __attribute__((ext_vector_type(4)));
typedef __bf16 bf16x8 __attribute__((ext_vector_type(8)));
typedef float  f32x4  __attribute__((ext_vector_type(4)));

#define MFMA16(a, b, c) __builtin_amdgcn_mfma_f32_16x16x32_bf16((a), (b), (c), 0, 0, 0)

// R8: wave-per-batch (zero barriers, R7 frame) with restructured iteration:
//  * s2 = W2 @ sumMu, where sumMu comes free from the previous epilogue
//    (register accumulate + 4-step DPP butterfly). Computed as an EXACT fp32
//    VALU matvec (lane=q, W2 row streamed from global -- 16KB, L1-resident).
//    Deletes R7's pass1 + rowsum machinery: 64 MFMAs/iter instead of 192,
//    no w2l registers. absmax evidence (786432 invariant across R1-R7, incl.
//    exact-fp32-s2 rounds) says W2 precision beyond bf16 never mattered.
//  * muS packed 128x64 bf16 (16.4KB), XOR-swizzled: halfword chunk c (8 hw)
//    stored at c ^ (k&7). b128 fragment reads and b64 epilogue stores are
//    conflict-free (R7's stride-72 + b64 stores gave 3.57M conflict cycles).
//  * launch_bounds(64,3): VGPR cap 170 -> 3 waves/SIMD; live set ~160.
//    Tripwire: FETCH_SIZE >> 2.5MB means spills -> revert to (64,2).
__global__ __launch_bounds__(64, 3)
void qnet_kernel(const float* __restrict__ Xg, const float* __restrict__ Wg,
                 const float* __restrict__ W1g, const float* __restrict__ W2g,
                 const float* __restrict__ W3g, const float* __restrict__ W4g,
                 const float* __restrict__ W5g, const float* __restrict__ W6g,
                 const float* __restrict__ W7g, float* __restrict__ Outg)
{
    __shared__ __align__(16) bf16 muS[128 * 64];   // 16384 B, packed + swizzled
    __shared__ __align__(16) float uS[64];         // 256 B
    __shared__ __align__(16) float smS[64];        // 256 B  sumMu (per-iter + readout)
    __shared__ __align__(16) float s2S[64];        // 256 B  s2 redistribute

    const int lane = threadIdx.x;      // one wave
    const int b    = blockIdx.x;
    const int l15  = lane & 15;
    const int quad = lane >> 4;
    const int sw   = l15 & 7;          // swizzle key: k&7 == l15&7 for k=16kt+l15

    // ---------------- per-batch vectors ----------------
    float xv0 = Xg[b * 128 + lane], xv1 = Xg[b * 128 + 64 + lane];
    float wv0 = Wg[b * 128 + lane], wv1 = Wg[b * 128 + 64 + lane];

    float Ap = fmaxf(wv0, 0.f) + fmaxf(wv1, 0.f);
    float Bn = fmaxf(-wv0, 0.f) + fmaxf(-wv1, 0.f);
#pragma unroll
    for (int m = 1; m < 64; m <<= 1) { Ap += __shfl_xor(Ap, m); Bn += __shfl_xor(Bn, m); }

    float xk[8], apk[8], bnk[8];
#pragma unroll
    for (int kt = 0; kt < 8; ++kt) {
        const int src = (kt & 3) * 16 + l15;
        float xs_ = (kt < 4) ? __shfl(xv0, src) : __shfl(xv1, src);
        float ws_ = (kt < 4) ? __shfl(wv0, src) : __shfl(wv1, src);
        xk[kt]  = xs_;
        apk[kt] = Ap - fmaxf(ws_, 0.f);
        bnk[kt] = Bn - fmaxf(-ws_, 0.f);
    }

    // v3p/v3m at q=lane (exact fp32), then distribute to (qt,e) epilogue layout
    float sp = 0.f, sm = 0.f;
#pragma unroll
    for (int c = 0; c < 16; ++c) {
        f32x4 w4 = *(const f32x4*)&W4g[c * 4];
        f32x4 w3 = *(const f32x4*)&W3g[lane * 64 + c * 4];
#pragma unroll
        for (int e = 0; e < 4; ++e) {
            sp += fmaxf(w4[e], 0.f) * w3[e];
            sm += fmaxf(-w4[e], 0.f) * w3[e];
        }
    }
    float w1C[16], v3pC[16], v3mC[16];
#pragma unroll
    for (int qt = 0; qt < 4; ++qt) {
        f32x4 w1v = *(const f32x4*)&W1g[qt * 16 + quad * 4];
#pragma unroll
        for (int e = 0; e < 4; ++e) {
            const int q = qt * 16 + quad * 4 + e;
            v3pC[qt * 4 + e] = __shfl(sp, q);
            v3mC[qt * 4 + e] = __shfl(sm, q);
            w1C[qt * 4 + e]  = w1v[e];
        }
    }

    // u[p=lane] = W5b @ W7[:,p] -> uS
    {
        float u = 0.f;
#pragma unroll
        for (int c = 0; c < 16; ++c) {
            f32x4 w5v = *(const f32x4*)&W5g[64 + c * 4];
#pragma unroll
            for (int e = 0; e < 4; ++e) u += w5v[e] * W7g[(c * 4 + e) * 64 + lane];
        }
        uS[lane] = u;
    }

    // W2 A-fragments (bf16 hi only)
    bf16x8 w2h[4][2];
#pragma unroll
    for (int qt = 0; qt < 4; ++qt)
#pragma unroll
        for (int s = 0; s < 2; ++s) {
            const float* src = &W2g[(qt * 16 + l15) * 64 + s * 32 + quad * 8];
            f32x4 f0 = *(const f32x4*)src;
            f32x4 f1 = *(const f32x4*)(src + 4);
            bf16x8 h;
#pragma unroll
            for (int e = 0; e < 4; ++e) { h[e] = (bf16)f0[e]; h[4 + e] = (bf16)f1[e]; }
            w2h[qt][s] = h;
        }

    // ---------------- mu1 = relu(base), exact fp32; accumulate smv ----------------
    float smv[16];
#pragma unroll
    for (int i = 0; i < 16; ++i) smv[i] = 0.f;
#pragma unroll
    for (int kt = 0; kt < 8; ++kt) {
        const int k = kt * 16 + l15;
#pragma unroll
        for (int qt = 0; qt < 4; ++qt) {
            bf16x4 h;
#pragma unroll
            for (int e = 0; e < 4; ++e) {
                float t = fmaf(xk[kt], w1C[qt * 4 + e],
                          fmaf(apk[kt], v3pC[qt * 4 + e], bnk[kt] * v3mC[qt * 4 + e]));
                float v = fmaxf(t, 0.f);
                smv[qt * 4 + e] += v;
                h[e] = (bf16)v;
            }
            *(bf16x4*)&muS[k * 64 + ((2 * qt + (quad >> 1)) ^ sw) * 8 + 4 * (quad & 1)] = h;
        }
    }

    // ---------------- 3 iterations, zero barriers ----------------
    const f32x4 zero4 = {0.f, 0.f, 0.f, 0.f};
    for (int it = 0; it < 3; ++it) {
        // sumMu: l15 butterfly (DPP-class shuffles) + publish to smS
#pragma unroll
        for (int m = 1; m <= 8; m <<= 1)
#pragma unroll
            for (int i = 0; i < 16; ++i) smv[i] += __shfl_xor(smv[i], m);
        if (l15 == 0) {
#pragma unroll
            for (int qt = 0; qt < 4; ++qt) {
                f32x4 v = {smv[qt * 4], smv[qt * 4 + 1], smv[qt * 4 + 2], smv[qt * 4 + 3]};
                *(f32x4*)&smS[qt * 16 + quad * 4] = v;
            }
        }
        // s2[q=lane] = sumMu @ W2[lane,:]  -- exact fp32, W2 row L1-resident
        {
            float a0 = 0.f, a1 = 0.f, a2 = 0.f, a3 = 0.f;
#pragma unroll
            for (int c = 0; c < 16; ++c) {
                f32x4 sv = *(const f32x4*)&smS[c * 4];
                f32x4 wv = *(const f32x4*)&W2g[lane * 64 + c * 4];
                a0 = fmaf(sv[0], wv[0], a0); a1 = fmaf(sv[1], wv[1], a1);
                a2 = fmaf(sv[2], wv[2], a2); a3 = fmaf(sv[3], wv[3], a3);
            }
            s2S[lane] = (a0 + a1) + (a2 + a3);
        }
        f32x4 s2q[4];
#pragma unroll
        for (int qt = 0; qt < 4; ++qt) s2q[qt] = *(const f32x4*)&s2S[qt * 16 + quad * 4];

        // main pass: 64 MFMAs + fused epilogue (base recomputed fp32-exact)
#pragma unroll
        for (int i = 0; i < 16; ++i) smv[i] = 0.f;
#pragma unroll
        for (int kt = 0; kt < 8; ++kt) {
            const int k = kt * 16 + l15;
            bf16x8 m0 = *(const bf16x8*)&muS[k * 64 + ((quad) ^ sw) * 8];
            bf16x8 m1 = *(const bf16x8*)&muS[k * 64 + ((4 + quad) ^ sw) * 8];
#pragma unroll
            for (int qt = 0; qt < 4; ++qt) {
                f32x4 a = MFMA16(w2h[qt][0], m0, zero4);
                a = MFMA16(w2h[qt][1], m1, a);
                bf16x4 h;
#pragma unroll
                for (int e = 0; e < 4; ++e) {
                    float t = fmaf(xk[kt], w1C[qt * 4 + e],
                              fmaf(apk[kt], v3pC[qt * 4 + e], bnk[kt] * v3mC[qt * 4 + e]));
                    float v = fmaxf(t + s2q[qt][e] - a[e], 0.f);
                    smv[qt * 4 + e] += v;
                    h[e] = (bf16)v;
                }
                *(bf16x4*)&muS[k * 64 + ((2 * qt + (quad >> 1)) ^ sw) * 8 + 4 * (quad & 1)] = h;
            }
        }
    }

    // ---------------- readout (wave-internal) ----------------
#pragma unroll
    for (int m = 1; m <= 8; m <<= 1)
#pragma unroll
        for (int i = 0; i < 16; ++i) smv[i] += __shfl_xor(smv[i], m);
    if (l15 == 0) {
#pragma unroll
        for (int qt = 0; qt < 4; ++qt) {
            f32x4 v = {smv[qt * 4], smv[qt * 4 + 1], smv[qt * 4 + 2], smv[qt * 4 + 3]};
            *(f32x4*)&smS[qt * 16 + quad * 4] = v;
        }
    }

    float pl = 0.f;
#pragma unroll
    for (int c = 0; c < 16; ++c) {
        f32x4 sv = *(const f32x4*)&smS[c * 4];
        f32x4 w6 = *(const f32x4*)&W6g[lane * 64 + c * 4];
#pragma unroll
        for (int e = 0; e < 4; ++e) pl = fmaf(sv[e], w6[e], pl);
    }
    float qa = fmaxf(pl, 0.f) * W5g[lane];
#pragma unroll
    for (int m = 1; m < 64; m <<= 1) qa += __shfl_xor(qa, m);

    f32x4 uf[2][2];
#pragma unroll
    for (int s = 0; s < 2; ++s) {
        uf[s][0] = *(const f32x4*)&uS[s * 32 + quad * 8];
        uf[s][1] = *(const f32x4*)&uS[s * 32 + quad * 8 + 4];
    }

    float res[8];
#pragma unroll
    for (int kt = 0; kt < 8; ++kt) {
        const int k = kt * 16 + l15;
        bf16x8 m0 = *(const bf16x8*)&muS[k * 64 + ((quad) ^ sw) * 8];
        bf16x8 m1 = *(const bf16x8*)&muS[k * 64 + ((4 + quad) ^ sw) * 8];
        float r = 0.f;
#pragma unroll
        for (int j = 0; j < 4; ++j) {
            r = fmaf((float)m0[j],     uf[0][0][j], r);
            r = fmaf((float)m0[4 + j], uf[0][1][j], r);
            r = fmaf((float)m1[j],     uf[1][0][j], r);
            r = fmaf((float)m1[4 + j], uf[1][1][j], r);
        }
        r += __shfl_xor(r, 16); r += __shfl_xor(r, 32);
        res[kt] = r;
    }
    float rA0 = (quad & 1) ? res[1] : res[0];
    float rA1 = (quad & 1) ? res[3] : res[2];
    float rA  = (quad & 2) ? rA1 : rA0;
    float rB0 = (quad & 1) ? res[5] : res[4];
    float rB1 = (quad & 1) ? res[7] : res[6];
    float rB  = (quad & 2) ? rB1 : rB0;
    Outg[b * 128 + lane]      = qa + rA;   // k = lane       (kt = quad)
    Outg[b * 128 + 64 + lane] = qa + rB;   // k = lane + 64  (kt = quad + 4)
}

extern "C" void kernel_launch(void* const* d_in, const int* in_sizes, int n_in,
                              void* d_out, int out_size, void* d_ws, size_t ws_size,
                              hipStream_t stream) {
    (void)n_in; (void)d_ws; (void)ws_size; (void)out_size;
    const int B = in_sizes[0] >> 7;   // 4096
    qnet_kernel<<<B, 64, 0, stream>>>(
        (const float*)d_in[0], (const float*)d_in[1], (const float*)d_in[2],
        (const float*)d_in[3], (const float*)d_in[4], (const float*)d_in[5],
        (const float*)d_in[6], (const float*)d_in[7], (const float*)d_in[8],
        (float*)d_out);
}

// Round 9
// 337.128 us; speedup vs baseline: 1.3234x; 1.3234x over previous
//
#include <hip/hip_runtime.h>

typedef __bf16 bf16;
typedef __bf16 bf16x4 __attribute__((ext_vector_type(4)));
typedef __bf16 bf16x8 __attribute__((ext_vector_type(8)));
typedef float  f32x4  __attribute__((ext_vector_type(4)));

#define MFMA16(a, b, c) __builtin_amdgcn_mfma_f32_16x16x32_bf16((a), (b), (c), 0, 0, 0)

// R9 = R8 structure at __launch_bounds__(64,2).
// LAUNCH-BOUNDS RULE (3 strikes: R2 cap102, R4 cap128->VGPR64/26MB spill,
// R8 cap170->VGPR84/364MB spill): NEVER set min-waves>2 on this kernel.
// The allocator over-squeezes far below the nominal cap and spills the hot loop.
// R8 structure recap:
//  * s2 = W2 @ sumMu as EXACT fp32 VALU matvec (W2 rows L1-resident);
//    sumMu free from epilogue accumulate + 4-step l15 butterfly.
//    64 MFMAs/iter (vs R7's 192), no w2l registers.
//  * muS packed 128x64 bf16 (16.4KB), XOR-swizzled (chunk ^ (k&7)):
//    conflict-free b128 reads + b64 writes.
//  * Zero __syncthreads anywhere (wave-per-batch, all LDS wave-private).
__global__ __launch_bounds__(64, 2)
void qnet_kernel(const float* __restrict__ Xg, const float* __restrict__ Wg,
                 const float* __restrict__ W1g, const float* __restrict__ W2g,
                 const float* __restrict__ W3g, const float* __restrict__ W4g,
                 const float* __restrict__ W5g, const float* __restrict__ W6g,
                 const float* __restrict__ W7g, float* __restrict__ Outg)
{
    __shared__ __align__(16) bf16 muS[128 * 64];   // 16384 B, packed + swizzled
    __shared__ __align__(16) float uS[64];         // 256 B
    __shared__ __align__(16) float smS[64];        // 256 B  sumMu (per-iter + readout)
    __shared__ __align__(16) float s2S[64];        // 256 B  s2 redistribute

    const int lane = threadIdx.x;      // one wave
    const int b    = blockIdx.x;
    const int l15  = lane & 15;
    const int quad = lane >> 4;
    const int sw   = l15 & 7;          // swizzle key: k&7 == l15&7 for k=16kt+l15

    // ---------------- per-batch vectors ----------------
    float xv0 = Xg[b * 128 + lane], xv1 = Xg[b * 128 + 64 + lane];
    float wv0 = Wg[b * 128 + lane], wv1 = Wg[b * 128 + 64 + lane];

    float Ap = fmaxf(wv0, 0.f) + fmaxf(wv1, 0.f);
    float Bn = fmaxf(-wv0, 0.f) + fmaxf(-wv1, 0.f);
#pragma unroll
    for (int m = 1; m < 64; m <<= 1) { Ap += __shfl_xor(Ap, m); Bn += __shfl_xor(Bn, m); }

    float xk[8], apk[8], bnk[8];
#pragma unroll
    for (int kt = 0; kt < 8; ++kt) {
        const int src = (kt & 3) * 16 + l15;
        float xs_ = (kt < 4) ? __shfl(xv0, src) : __shfl(xv1, src);
        float ws_ = (kt < 4) ? __shfl(wv0, src) : __shfl(wv1, src);
        xk[kt]  = xs_;
        apk[kt] = Ap - fmaxf(ws_, 0.f);
        bnk[kt] = Bn - fmaxf(-ws_, 0.f);
    }

    // v3p/v3m at q=lane (exact fp32), then distribute to (qt,e) epilogue layout
    float sp = 0.f, sm = 0.f;
#pragma unroll
    for (int c = 0; c < 16; ++c) {
        f32x4 w4 = *(const f32x4*)&W4g[c * 4];
        f32x4 w3 = *(const f32x4*)&W3g[lane * 64 + c * 4];
#pragma unroll
        for (int e = 0; e < 4; ++e) {
            sp += fmaxf(w4[e], 0.f) * w3[e];
            sm += fmaxf(-w4[e], 0.f) * w3[e];
        }
    }
    float w1C[16], v3pC[16], v3mC[16];
#pragma unroll
    for (int qt = 0; qt < 4; ++qt) {
        f32x4 w1v = *(const f32x4*)&W1g[qt * 16 + quad * 4];
#pragma unroll
        for (int e = 0; e < 4; ++e) {
            const int q = qt * 16 + quad * 4 + e;
            v3pC[qt * 4 + e] = __shfl(sp, q);
            v3mC[qt * 4 + e] = __shfl(sm, q);
            w1C[qt * 4 + e]  = w1v[e];
        }
    }

    // u[p=lane] = W5b @ W7[:,p] -> uS
    {
        float u = 0.f;
#pragma unroll
        for (int c = 0; c < 16; ++c) {
            f32x4 w5v = *(const f32x4*)&W5g[64 + c * 4];
#pragma unroll
            for (int e = 0; e < 4; ++e) u += w5v[e] * W7g[(c * 4 + e) * 64 + lane];
        }
        uS[lane] = u;
    }

    // W2 A-fragments (bf16 hi only)
    bf16x8 w2h[4][2];
#pragma unroll
    for (int qt = 0; qt < 4; ++qt)
#pragma unroll
        for (int s = 0; s < 2; ++s) {
            const float* src = &W2g[(qt * 16 + l15) * 64 + s * 32 + quad * 8];
            f32x4 f0 = *(const f32x4*)src;
            f32x4 f1 = *(const f32x4*)(src + 4);
            bf16x8 h;
#pragma unroll
            for (int e = 0; e < 4; ++e) { h[e] = (bf16)f0[e]; h[4 + e] = (bf16)f1[e]; }
            w2h[qt][s] = h;
        }

    // ---------------- mu1 = relu(base), exact fp32; accumulate smv ----------------
    float smv[16];
#pragma unroll
    for (int i = 0; i < 16; ++i) smv[i] = 0.f;
#pragma unroll
    for (int kt = 0; kt < 8; ++kt) {
        const int k = kt * 16 + l15;
#pragma unroll
        for (int qt = 0; qt < 4; ++qt) {
            bf16x4 h;
#pragma unroll
            for (int e = 0; e < 4; ++e) {
                float t = fmaf(xk[kt], w1C[qt * 4 + e],
                          fmaf(apk[kt], v3pC[qt * 4 + e], bnk[kt] * v3mC[qt * 4 + e]));
                float v = fmaxf(t, 0.f);
                smv[qt * 4 + e] += v;
                h[e] = (bf16)v;
            }
            *(bf16x4*)&muS[k * 64 + ((2 * qt + (quad >> 1)) ^ sw) * 8 + 4 * (quad & 1)] = h;
        }
    }

    // ---------------- 3 iterations, zero barriers ----------------
    const f32x4 zero4 = {0.f, 0.f, 0.f, 0.f};
    for (int it = 0; it < 3; ++it) {
        // sumMu: l15 butterfly + publish to smS
#pragma unroll
        for (int m = 1; m <= 8; m <<= 1)
#pragma unroll
            for (int i = 0; i < 16; ++i) smv[i] += __shfl_xor(smv[i], m);
        if (l15 == 0) {
#pragma unroll
            for (int qt = 0; qt < 4; ++qt) {
                f32x4 v = {smv[qt * 4], smv[qt * 4 + 1], smv[qt * 4 + 2], smv[qt * 4 + 3]};
                *(f32x4*)&smS[qt * 16 + quad * 4] = v;
            }
        }
        // s2[q=lane] = sumMu @ W2[lane,:]  -- exact fp32, W2 row L1-resident
        {
            float a0 = 0.f, a1 = 0.f, a2 = 0.f, a3 = 0.f;
#pragma unroll
            for (int c = 0; c < 16; ++c) {
                f32x4 sv = *(const f32x4*)&smS[c * 4];
                f32x4 wv = *(const f32x4*)&W2g[lane * 64 + c * 4];
                a0 = fmaf(sv[0], wv[0], a0); a1 = fmaf(sv[1], wv[1], a1);
                a2 = fmaf(sv[2], wv[2], a2); a3 = fmaf(sv[3], wv[3], a3);
            }
            s2S[lane] = (a0 + a1) + (a2 + a3);
        }
        f32x4 s2q[4];
#pragma unroll
        for (int qt = 0; qt < 4; ++qt) s2q[qt] = *(const f32x4*)&s2S[qt * 16 + quad * 4];

        // main pass: 64 MFMAs + fused epilogue (base recomputed fp32-exact)
#pragma unroll
        for (int i = 0; i < 16; ++i) smv[i] = 0.f;
#pragma unroll
        for (int kt = 0; kt < 8; ++kt) {
            const int k = kt * 16 + l15;
            bf16x8 m0 = *(const bf16x8*)&muS[k * 64 + ((quad) ^ sw) * 8];
            bf16x8 m1 = *(const bf16x8*)&muS[k * 64 + ((4 + quad) ^ sw) * 8];
#pragma unroll
            for (int qt = 0; qt < 4; ++qt) {
                f32x4 a = MFMA16(w2h[qt][0], m0, zero4);
                a = MFMA16(w2h[qt][1], m1, a);
                bf16x4 h;
#pragma unroll
                for (int e = 0; e < 4; ++e) {
                    float t = fmaf(xk[kt], w1C[qt * 4 + e],
                              fmaf(apk[kt], v3pC[qt * 4 + e], bnk[kt] * v3mC[qt * 4 + e]));
                    float v = fmaxf(t + s2q[qt][e] - a[e], 0.f);
                    smv[qt * 4 + e] += v;
                    h[e] = (bf16)v;
                }
                *(bf16x4*)&muS[k * 64 + ((2 * qt + (quad >> 1)) ^ sw) * 8 + 4 * (quad & 1)] = h;
            }
        }
    }

    // ---------------- readout (wave-internal) ----------------
#pragma unroll
    for (int m = 1; m <= 8; m <<= 1)
#pragma unroll
        for (int i = 0; i < 16; ++i) smv[i] += __shfl_xor(smv[i], m);
    if (l15 == 0) {
#pragma unroll
        for (int qt = 0; qt < 4; ++qt) {
            f32x4 v = {smv[qt * 4], smv[qt * 4 + 1], smv[qt * 4 + 2], smv[qt * 4 + 3]};
            *(f32x4*)&smS[qt * 16 + quad * 4] = v;
        }
    }

    float pl = 0.f;
#pragma unroll
    for (int c = 0; c < 16; ++c) {
        f32x4 sv = *(const f32x4*)&smS[c * 4];
        f32x4 w6 = *(const f32x4*)&W6g[lane * 64 + c * 4];
#pragma unroll
        for (int e = 0; e < 4; ++e) pl = fmaf(sv[e], w6[e], pl);
    }
    float qa = fmaxf(pl, 0.f) * W5g[lane];
#pragma unroll
    for (int m = 1; m < 64; m <<= 1) qa += __shfl_xor(qa, m);

    f32x4 uf[2][2];
#pragma unroll
    for (int s = 0; s < 2; ++s) {
        uf[s][0] = *(const f32x4*)&uS[s * 32 + quad * 8];
        uf[s][1] = *(const f32x4*)&uS[s * 32 + quad * 8 + 4];
    }

    float res[8];
#pragma unroll
    for (int kt = 0; kt < 8; ++kt) {
        const int k = kt * 16 + l15;
        bf16x8 m0 = *(const bf16x8*)&muS[k * 64 + ((quad) ^ sw) * 8];
        bf16x8 m1 = *(const bf16x8*)&muS[k * 64 + ((4 + quad) ^ sw) * 8];
        float r = 0.f;
#pragma unroll
        for (int j = 0; j < 4; ++j) {
            r = fmaf((float)m0[j],     uf[0][0][j], r);
            r = fmaf((float)m0[4 + j], uf[0][1][j], r);
            r = fmaf((float)m1[j],     uf[1][0][j], r);
            r = fmaf((float)m1[4 + j], uf[1][1][j], r);
        }
        r += __shfl_xor(r, 16); r += __shfl_xor(r, 32);
        res[kt] = r;
    }
    float rA0 = (quad & 1) ? res[1] : res[0];
    float rA1 = (quad & 1) ? res[3] : res[2];
    float rA  = (quad & 2) ? rA1 : rA0;
    float rB0 = (quad & 1) ? res[5] : res[4];
    float rB1 = (quad & 1) ? res[7] : res[6];
    float rB  = (quad & 2) ? rB1 : rB0;
    Outg[b * 128 + lane]      = qa + rA;   // k = lane       (kt = quad)
    Outg[b * 128 + 64 + lane] = qa + rB;   // k = lane + 64  (kt = quad + 4)
}

extern "C" void kernel_launch(void* const* d_in, const int* in_sizes, int n_in,
                              void* d_out, int out_size, void* d_ws, size_t ws_size,
                              hipStream_t stream) {
    (void)n_in; (void)d_ws; (void)ws_size; (void)out_size;
    const int B = in_sizes[0] >> 7;   // 4096
    qnet_kernel<<<B, 64, 0, stream>>>(
        (const float*)d_in[0], (const float*)d_in[1], (const float*)d_in[2],
        (const float*)d_in[3], (const float*)d_in[4], (const float*)d_in[5],
        (const float*)d_in[6], (const float*)d_in[7], (const float*)d_in[8],
        (float*)d_out);
}

// Round 10
// 162.048 us; speedup vs baseline: 2.7532x; 2.0804x over previous
//
#include <hip/hip_runtime.h>

typedef __bf16 bf16;
typedef __bf16 bf16x4 __attribute__((ext_vector_type(4)));
typedef __bf16 bf16x8 __attribute__((ext_vector_type(8)));
typedef float  f32x4  __attribute__((ext_vector_type(4)));

#define MFMA16(a, b, c) __builtin_amdgcn_mfma_f32_16x16x32_bf16((a), (b), (c), 0, 0, 0)

// R10: TWO waves per batch element (128 thr), k-split, ONE barrier per iteration.
//  * Wave w owns k in [64w, 64w+64) (4 kt tiles). Flipped GEMM (acc = W2·muT,
//    D col = k) keeps ALL muS reads/writes wave-private -> only coupling is the
//    s2 rowsum combine: l15-butterfly -> LDS partial -> __syncthreads -> add.
//    Ping-pong partial buffer makes 1 barrier/iter safe (WAR-free).
//  * SINGLE PASS: all 16 acc f32x4 stay live across the barrier. acc/W2-frags
//    live on the AGPR side of the unified file (MFMA operands/results), so the
//    ARCH-VGPR live set stays ~<=128. R9 lesson: arch live >128 spills even at
//    (_,2) -- the allocator pins arch at 128 (accum_offset) when MFMA is used.
//    64 MFMAs/wave/iter (hi+lo W2), 8 LDS b128 reads/iter (R7: 192 / 32).
//  * muS packed 128x64 bf16 XOR-swizzled (mu[k][q] at k*64+((q>>3)^(k&7))*8+(q&7)):
//    conflict-free-ish b128 reads / b64 writes (R7 stride-72: 3.57M conflict cyc).
//  * LDS 18176 B -> 9 blocks/CU = 18 waves/CU = 4.5 waves/SIMD (R7: 2/SIMD).
//  * Epilogue acc is hi+lo W2 (better than R7's hi-only): absmax <= 786432.
// LAUNCH-BOUNDS RULE (R2/R4/R8 strikes): never min-waves>2.
// SPILL TRIPWIRE: FETCH_SIZE >> 2.5MB or WRITE_SIZE >> 2KB => arch spill =>
// fallback: drop live acc, recompute pass2 (R7 style) to shed arch pressure.
__global__ __launch_bounds__(128, 2)
void qnet_kernel(const float* __restrict__ Xg, const float* __restrict__ Wg,
                 const float* __restrict__ W1g, const float* __restrict__ W2g,
                 const float* __restrict__ W3g, const float* __restrict__ W4g,
                 const float* __restrict__ W5g, const float* __restrict__ W6g,
                 const float* __restrict__ W7g, float* __restrict__ Outg)
{
    __shared__ __align__(16) bf16 muS[128 * 64];   // 16384 B, packed + swizzled
    __shared__ __align__(16) float prt[2][2][64];  // 1024 B  s2 partials [buf][wave][q]
    __shared__ __align__(16) float csB[2][64];     // 512 B   colsum partials [wave][p]
    __shared__ __align__(16) float uS[64];         // 256 B

    const int t    = threadIdx.x;
    const int lane = t & 63;
    const int w    = t >> 6;          // wave 0/1: owns k in [64w, 64w+64)
    const int b    = blockIdx.x;
    const int l15  = lane & 15;
    const int quad = lane >> 4;
    const int sw   = l15 & 7;         // swizzle key (k&7 == l15&7)

    // ---------------- per-batch vectors (redundant per wave) ----------------
    float xv0 = Xg[b * 128 + lane], xv1 = Xg[b * 128 + 64 + lane];
    float wv0 = Wg[b * 128 + lane], wv1 = Wg[b * 128 + 64 + lane];

    float Ap = fmaxf(wv0, 0.f) + fmaxf(wv1, 0.f);
    float Bn = fmaxf(-wv0, 0.f) + fmaxf(-wv1, 0.f);
#pragma unroll
    for (int m = 1; m < 64; m <<= 1) { Ap += __shfl_xor(Ap, m); Bn += __shfl_xor(Bn, m); }

    // per-kt scalars, kt local 0..3; global k = 64w + 16kt + l15
    float xk[4], apk[4], bnk[4];
#pragma unroll
    for (int kt = 0; kt < 4; ++kt) {
        const int src = kt * 16 + l15;
        float xs_ = w ? __shfl(xv1, src) : __shfl(xv0, src);
        float ws_ = w ? __shfl(wv1, src) : __shfl(wv0, src);
        xk[kt]  = xs_;
        apk[kt] = Ap - fmaxf(ws_, 0.f);
        bnk[kt] = Bn - fmaxf(-ws_, 0.f);
    }

    // v3p/v3m at q=lane (exact fp32), distribute to (qt,e) epilogue layout
    float sp = 0.f, sm = 0.f;
#pragma unroll
    for (int c = 0; c < 16; ++c) {
        f32x4 w4 = *(const f32x4*)&W4g[c * 4];
        f32x4 w3 = *(const f32x4*)&W3g[lane * 64 + c * 4];
#pragma unroll
        for (int e = 0; e < 4; ++e) {
            sp += fmaxf(w4[e], 0.f) * w3[e];
            sm += fmaxf(-w4[e], 0.f) * w3[e];
        }
    }
    float w1C[16], v3pC[16], v3mC[16];
#pragma unroll
    for (int qt = 0; qt < 4; ++qt) {
        f32x4 w1v = *(const f32x4*)&W1g[qt * 16 + quad * 4];
#pragma unroll
        for (int e = 0; e < 4; ++e) {
            const int q = qt * 16 + quad * 4 + e;
            v3pC[qt * 4 + e] = __shfl(sp, q);
            v3mC[qt * 4 + e] = __shfl(sm, q);
            w1C[qt * 4 + e]  = w1v[e];
        }
    }

    // u[p=lane] = W5b @ W7[:,p]  (wave 0 only; visible to wave 1 after barriers)
    if (w == 0) {
        float u = 0.f;
#pragma unroll
        for (int c = 0; c < 16; ++c) {
            f32x4 w5v = *(const f32x4*)&W5g[64 + c * 4];
#pragma unroll
            for (int e = 0; e < 4; ++e) u += w5v[e] * W7g[(c * 4 + e) * 64 + lane];
        }
        uS[lane] = u;
    }

    // W2 A-fragments hi+lo (AGPR-side residents)
    bf16x8 w2h[4][2], w2l[4][2];
#pragma unroll
    for (int qt = 0; qt < 4; ++qt)
#pragma unroll
        for (int s = 0; s < 2; ++s) {
            const float* src = &W2g[(qt * 16 + l15) * 64 + s * 32 + quad * 8];
            f32x4 f0 = *(const f32x4*)src;
            f32x4 f1 = *(const f32x4*)(src + 4);
            bf16x8 h, l;
#pragma unroll
            for (int e = 0; e < 4; ++e) {
                bf16 h0 = (bf16)f0[e], h1 = (bf16)f1[e];
                h[e] = h0; h[4 + e] = h1;
                l[e]     = (bf16)(f0[e] - (float)h0);
                l[4 + e] = (bf16)(f1[e] - (float)h1);
            }
            w2h[qt][s] = h; w2l[qt][s] = l;
        }

    // ---------------- mu1 = relu(base), exact fp32 (own rows) ----------------
#pragma unroll
    for (int kt = 0; kt < 4; ++kt) {
        const int k = w * 64 + kt * 16 + l15;
#pragma unroll
        for (int qt = 0; qt < 4; ++qt) {
            bf16x4 h;
#pragma unroll
            for (int e = 0; e < 4; ++e) {
                float tb = fmaf(xk[kt], w1C[qt * 4 + e],
                           fmaf(apk[kt], v3pC[qt * 4 + e], bnk[kt] * v3mC[qt * 4 + e]));
                h[e] = (bf16)fmaxf(tb, 0.f);
            }
            *(bf16x4*)&muS[k * 64 + ((2 * qt + (quad >> 1)) ^ sw) * 8 + 4 * (quad & 1)] = h;
        }
    }

    // ---------------- 3 iterations, ONE barrier each ----------------
    const f32x4 zero4 = {0.f, 0.f, 0.f, 0.f};
    float smv[16];
#pragma unroll
    for (int i = 0; i < 16; ++i) smv[i] = 0.f;

    for (int it = 0; it < 3; ++it) {
        // single pass: acc live (AGPR), rs = rowsum accumulates alongside
        f32x4 acc[4][4];
        f32x4 rs[4] = {zero4, zero4, zero4, zero4};
#pragma unroll
        for (int kt = 0; kt < 4; ++kt) {
            const int k = w * 64 + kt * 16 + l15;
            bf16x8 m0 = *(const bf16x8*)&muS[k * 64 + ((quad) ^ sw) * 8];
            bf16x8 m1 = *(const bf16x8*)&muS[k * 64 + ((4 + quad) ^ sw) * 8];
#pragma unroll
            for (int qt = 0; qt < 4; ++qt) {
                f32x4 a = MFMA16(w2h[qt][0], m0, zero4);
                a = MFMA16(w2h[qt][1], m1, a);
                a = MFMA16(w2l[qt][0], m0, a);
                a = MFMA16(w2l[qt][1], m1, a);
                acc[kt][qt] = a;
                rs[qt] += a;
            }
        }
        // wave-local rowsum over the 16 cols: l15 butterfly
#pragma unroll
        for (int m = 1; m <= 8; m <<= 1)
#pragma unroll
            for (int qt = 0; qt < 4; ++qt)
#pragma unroll
                for (int e = 0; e < 4; ++e)
                    rs[qt][e] += __shfl_xor(rs[qt][e], m);
        if (l15 == 0) {
#pragma unroll
            for (int qt = 0; qt < 4; ++qt)
                *(f32x4*)&prt[it & 1][w][qt * 16 + quad * 4] = rs[qt];
        }
        __syncthreads();   // the ONE barrier (ping-pong -> WAR-free)

        // s2 combine + epilogue from LIVE acc (hi+lo -> best numerics yet)
#pragma unroll
        for (int qt = 0; qt < 4; ++qt) {
            f32x4 s2v = *(const f32x4*)&prt[it & 1][0][qt * 16 + quad * 4]
                      + *(const f32x4*)&prt[it & 1][1][qt * 16 + quad * 4];
#pragma unroll
            for (int kt = 0; kt < 4; ++kt) {
                const int k = w * 64 + kt * 16 + l15;
                bf16x4 h;
#pragma unroll
                for (int e = 0; e < 4; ++e) {
                    float tb = fmaf(xk[kt], w1C[qt * 4 + e],
                               fmaf(apk[kt], v3pC[qt * 4 + e], bnk[kt] * v3mC[qt * 4 + e]));
                    float v = fmaxf(tb + s2v[e] - acc[kt][qt][e], 0.f);
                    if (it == 2) smv[qt * 4 + e] += v;
                    h[e] = (bf16)v;
                }
                *(bf16x4*)&muS[k * 64 + ((2 * qt + (quad >> 1)) ^ sw) * 8 + 4 * (quad & 1)] = h;
            }
        }
    }

    // ---------------- readout ----------------
#pragma unroll
    for (int m = 1; m <= 8; m <<= 1)
#pragma unroll
        for (int i = 0; i < 16; ++i) smv[i] += __shfl_xor(smv[i], m);
    if (l15 == 0) {
#pragma unroll
        for (int qt = 0; qt < 4; ++qt) {
            f32x4 v = {smv[qt * 4], smv[qt * 4 + 1], smv[qt * 4 + 2], smv[qt * 4 + 3]};
            *(f32x4*)&csB[w][qt * 16 + quad * 4] = v;
        }
    }
    __syncthreads();   // colsum partials + uS visible

    float pl = 0.f;
#pragma unroll
    for (int c = 0; c < 16; ++c) {
        f32x4 s0 = *(const f32x4*)&csB[0][c * 4];
        f32x4 s1 = *(const f32x4*)&csB[1][c * 4];
        f32x4 w6 = *(const f32x4*)&W6g[lane * 64 + c * 4];
#pragma unroll
        for (int e = 0; e < 4; ++e) pl = fmaf(s0[e] + s1[e], w6[e], pl);
    }
    float qa = fmaxf(pl, 0.f) * W5g[lane];
#pragma unroll
    for (int m = 1; m < 64; m <<= 1) qa += __shfl_xor(qa, m);

    f32x4 uf[2][2];
#pragma unroll
    for (int s = 0; s < 2; ++s) {
        uf[s][0] = *(const f32x4*)&uS[s * 32 + quad * 8];
        uf[s][1] = *(const f32x4*)&uS[s * 32 + quad * 8 + 4];
    }

    float res[4];
#pragma unroll
    for (int kt = 0; kt < 4; ++kt) {
        const int k = w * 64 + kt * 16 + l15;
        bf16x8 m0 = *(const bf16x8*)&muS[k * 64 + ((quad) ^ sw) * 8];
        bf16x8 m1 = *(const bf16x8*)&muS[k * 64 + ((4 + quad) ^ sw) * 8];
        float r = 0.f;
#pragma unroll
        for (int j = 0; j < 4; ++j) {
            r = fmaf((float)m0[j],     uf[0][0][j], r);
            r = fmaf((float)m0[4 + j], uf[0][1][j], r);
            r = fmaf((float)m1[j],     uf[1][0][j], r);
            r = fmaf((float)m1[4 + j], uf[1][1][j], r);
        }
        r += __shfl_xor(r, 16); r += __shfl_xor(r, 32);
        res[kt] = r;
    }
    float r01 = (quad & 1) ? res[1] : res[0];
    float r23 = (quad & 1) ? res[3] : res[2];
    float rr  = (quad & 2) ? r23 : r01;
    Outg[b * 128 + w * 64 + lane] = qa + rr;   // k = 64w + quad*16 + l15 = 64w + lane
}

extern "C" void kernel_launch(void* const* d_in, const int* in_sizes, int n_in,
                              void* d_out, int out_size, void* d_ws, size_t ws_size,
                              hipStream_t stream) {
    (void)n_in; (void)d_ws; (void)ws_size; (void)out_size;
    const int B = in_sizes[0] >> 7;   // 4096
    qnet_kernel<<<B, 128, 0, stream>>>(
        (const float*)d_in[0], (const float*)d_in[1], (const float*)d_in[2],
        (const float*)d_in[3], (const float*)d_in[4], (const float*)d_in[5],
        (const float*)d_in[6], (const float*)d_in[7], (const float*)d_in[8],
        (float*)d_out);
}

// Round 11
// 136.294 us; speedup vs baseline: 3.2735x; 1.1890x over previous
//
#include <hip/hip_runtime.h>

typedef __bf16 bf16;
typedef __bf16 bf16x4 __attribute__((ext_vector_type(4)));
typedef __bf16 bf16x8 __attribute__((ext_vector_type(8)));
typedef float  f32x4  __attribute__((ext_vector_type(4)));

#define MFMA16(a, b, c) __builtin_amdgcn_mfma_f32_16x16x32_bf16((a), (b), (c), 0, 0, 0)

// R11 = R7 (best: 78.7us, zero barriers, wave-per-b) + two surgical fixes:
//  (a) muS packed 128x64 bf16, XOR-swizzled (q-chunk c stored at c^(k&7)):
//      b128 reads hit each 4-bank group at exactly line rate (conflict-free);
//      b64 stores <=2-way (free, m136). R7's stride-72 rows (144B = 36 banks)
//      overlapped banks -> 3.57M conflict cycles. LDS 18.9KB -> 16.9KB:
//      9 blocks/CU instead of 8.
//  (b) pass1 MFMA chains split 4-deep -> 2x 2-deep (hi-chain + lo-chain,
//      added after): 8 independent MFMA streams at 2 waves/SIMD.
// Everything else VERBATIM R7/R8 (both HW-validated):
//  * two-pass loop: pass1 hi+lo -> s2 rowsum via l15 butterfly; pass2 hi-only
//    recompute + fused exact-fp32 base epilogue. absmax 786432 class.
//  * zero __syncthreads (all LDS wave-private).
// LAUNCH-BOUNDS RULE (R2/R4/R8 strikes): never min-waves>2. SPILL TRIPWIRE:
// FETCH>>2.5MB or WRITE>>2KB => arch-VGPR live set exceeded 128 => back off.
__global__ __launch_bounds__(64, 2)
void qnet_kernel(const float* __restrict__ Xg, const float* __restrict__ Wg,
                 const float* __restrict__ W1g, const float* __restrict__ W2g,
                 const float* __restrict__ W3g, const float* __restrict__ W4g,
                 const float* __restrict__ W5g, const float* __restrict__ W6g,
                 const float* __restrict__ W7g, float* __restrict__ Outg)
{
    __shared__ __align__(16) bf16 muS[128 * 64];   // 16384 B, packed + swizzled
    __shared__ __align__(16) float uS[64];         // 256 B
    __shared__ __align__(16) float smS[64];        // 256 B

    const int lane = threadIdx.x;       // 0..63, one wave
    const int b    = blockIdx.x;
    const int l15  = lane & 15;
    const int quad = lane >> 4;
    const int sw   = l15 & 7;           // swizzle key: k&7 == l15&7 for k=16kt+l15

    // ---------------- per-batch vectors (registers only) ----------------
    float xv0 = Xg[b * 128 + lane], xv1 = Xg[b * 128 + 64 + lane];
    float wv0 = Wg[b * 128 + lane], wv1 = Wg[b * 128 + 64 + lane];

    float Ap = fmaxf(wv0, 0.f) + fmaxf(wv1, 0.f);
    float Bn = fmaxf(-wv0, 0.f) + fmaxf(-wv1, 0.f);
#pragma unroll
    for (int m = 1; m < 64; m <<= 1) { Ap += __shfl_xor(Ap, m); Bn += __shfl_xor(Bn, m); }

    // per-kt scalars via shfl (k = kt*16 + l15)
    float xk[8], apk[8], bnk[8];
#pragma unroll
    for (int kt = 0; kt < 8; ++kt) {
        const int src = (kt & 3) * 16 + l15;
        float xs_ = (kt < 4) ? __shfl(xv0, src) : __shfl(xv1, src);
        float ws_ = (kt < 4) ? __shfl(wv0, src) : __shfl(wv1, src);
        xk[kt]  = xs_;
        apk[kt] = Ap - fmaxf(ws_, 0.f);
        bnk[kt] = Bn - fmaxf(-ws_, 0.f);
    }

    // v3p/v3m at q=lane (exact fp32), distribute to (qt,e) epilogue layout
    float sp = 0.f, sm = 0.f;
#pragma unroll
    for (int c = 0; c < 16; ++c) {
        f32x4 w4 = *(const f32x4*)&W4g[c * 4];
        f32x4 w3 = *(const f32x4*)&W3g[lane * 64 + c * 4];
#pragma unroll
        for (int e = 0; e < 4; ++e) {
            sp += fmaxf(w4[e], 0.f) * w3[e];
            sm += fmaxf(-w4[e], 0.f) * w3[e];
        }
    }
    float w1C[16], v3pC[16], v3mC[16];
#pragma unroll
    for (int qt = 0; qt < 4; ++qt) {
        f32x4 w1v = *(const f32x4*)&W1g[qt * 16 + quad * 4];
#pragma unroll
        for (int e = 0; e < 4; ++e) {
            const int q = qt * 16 + quad * 4 + e;
            v3pC[qt * 4 + e] = __shfl(sp, q);
            v3mC[qt * 4 + e] = __shfl(sm, q);
            w1C[qt * 4 + e]  = w1v[e];
        }
    }

    // u[p=lane] = W5b @ W7[:,p] -> uS (wave-private LDS)
    {
        float u = 0.f;
#pragma unroll
        for (int c = 0; c < 16; ++c) {
            f32x4 w5v = *(const f32x4*)&W5g[64 + c * 4];
#pragma unroll
            for (int e = 0; e < 4; ++e) u += w5v[e] * W7g[(c * 4 + e) * 64 + lane];
        }
        uS[lane] = u;
    }

    // W2 A-fragments hi+lo (double-bf16) -- AGPR-side residents
    bf16x8 w2h[4][2], w2l[4][2];
#pragma unroll
    for (int qt = 0; qt < 4; ++qt)
#pragma unroll
        for (int s = 0; s < 2; ++s) {
            const float* src = &W2g[(qt * 16 + l15) * 64 + s * 32 + quad * 8];
            f32x4 f0 = *(const f32x4*)src;
            f32x4 f1 = *(const f32x4*)(src + 4);
            bf16x8 h, l;
#pragma unroll
            for (int e = 0; e < 4; ++e) {
                bf16 h0 = (bf16)f0[e], h1 = (bf16)f1[e];
                h[e] = h0; h[4 + e] = h1;
                l[e]     = (bf16)(f0[e] - (float)h0);
                l[4 + e] = (bf16)(f1[e] - (float)h1);
            }
            w2h[qt][s] = h; w2l[qt][s] = l;
        }

    // ---------------- mu1 = relu(base), exact fp32 ----------------
#pragma unroll
    for (int kt = 0; kt < 8; ++kt) {
        const int row = (kt * 16 + l15) * 64;
#pragma unroll
        for (int qt = 0; qt < 4; ++qt) {
            bf16x4 h;
#pragma unroll
            for (int e = 0; e < 4; ++e) {
                float t = fmaf(xk[kt], w1C[qt * 4 + e],
                          fmaf(apk[kt], v3pC[qt * 4 + e], bnk[kt] * v3mC[qt * 4 + e]));
                h[e] = (bf16)fmaxf(t, 0.f);
            }
            *(bf16x4*)&muS[row + ((2 * qt + (quad >> 1)) ^ sw) * 8 + 4 * (quad & 1)] = h;
        }
    }

    // ---------------- 3 iterations, zero barriers ----------------
    const f32x4 zero4 = {0.f, 0.f, 0.f, 0.f};
    float smv[16];
#pragma unroll
    for (int i = 0; i < 16; ++i) smv[i] = 0.f;

    for (int it = 0; it < 3; ++it) {
        // pass1: s2 = rowsum_k(W2·muT), hi+lo W2 -- split 2+2 chains for ILP
        f32x4 rs[4] = {zero4, zero4, zero4, zero4};
#pragma unroll
        for (int kt = 0; kt < 8; ++kt) {
            const int row = (kt * 16 + l15) * 64;
            bf16x8 m0 = *(const bf16x8*)&muS[row + ((quad) ^ sw) * 8];
            bf16x8 m1 = *(const bf16x8*)&muS[row + ((4 + quad) ^ sw) * 8];
#pragma unroll
            for (int qt = 0; qt < 4; ++qt) {
                f32x4 a = MFMA16(w2h[qt][0], m0, zero4);
                a = MFMA16(w2h[qt][1], m1, a);
                f32x4 c = MFMA16(w2l[qt][0], m0, zero4);
                c = MFMA16(w2l[qt][1], m1, c);
                rs[qt] += a + c;
            }
        }
#pragma unroll
        for (int m = 1; m <= 8; m <<= 1)
#pragma unroll
            for (int qt = 0; qt < 4; ++qt)
#pragma unroll
                for (int e = 0; e < 4; ++e)
                    rs[qt][e] += __shfl_xor(rs[qt][e], m);
        // rs[qt][e] = s2[q] for q = qt*16+quad*4+e, on every lane

        // pass2: recompute acc (hi W2) + fused epilogue, stores wave-private
#pragma unroll
        for (int kt = 0; kt < 8; ++kt) {
            const int row = (kt * 16 + l15) * 64;
            bf16x8 m0 = *(const bf16x8*)&muS[row + ((quad) ^ sw) * 8];
            bf16x8 m1 = *(const bf16x8*)&muS[row + ((4 + quad) ^ sw) * 8];
#pragma unroll
            for (int qt = 0; qt < 4; ++qt) {
                f32x4 a = MFMA16(w2h[qt][0], m0, zero4);
                a = MFMA16(w2h[qt][1], m1, a);
                bf16x4 h;
#pragma unroll
                for (int e = 0; e < 4; ++e) {
                    float t = fmaf(xk[kt], w1C[qt * 4 + e], rs[qt][e]);
                    t = fmaf(apk[kt], v3pC[qt * 4 + e], t);
                    t = fmaf(bnk[kt], v3mC[qt * 4 + e], t);
                    float v = fmaxf(t - a[e], 0.f);
                    h[e] = (bf16)v;
                    if (it == 2) smv[qt * 4 + e] += v;   // colsum of final mu
                }
                *(bf16x4*)&muS[row + ((2 * qt + (quad >> 1)) ^ sw) * 8 + 4 * (quad & 1)] = h;
            }
        }
    }

    // ---------------- readout (wave-internal) ----------------
#pragma unroll
    for (int m = 1; m <= 8; m <<= 1)
#pragma unroll
        for (int i = 0; i < 16; ++i) smv[i] += __shfl_xor(smv[i], m);
    if (l15 == 0) {
#pragma unroll
        for (int qt = 0; qt < 4; ++qt) {
            f32x4 v = {smv[qt * 4], smv[qt * 4 + 1], smv[qt * 4 + 2], smv[qt * 4 + 3]};
            *(f32x4*)&smS[qt * 16 + quad * 4] = v;
        }
    }

    float pl = 0.f;
#pragma unroll
    for (int c = 0; c < 16; ++c) {
        f32x4 sv = *(const f32x4*)&smS[c * 4];
        f32x4 w6 = *(const f32x4*)&W6g[lane * 64 + c * 4];
#pragma unroll
        for (int e = 0; e < 4; ++e) pl = fmaf(sv[e], w6[e], pl);
    }
    float qa = fmaxf(pl, 0.f) * W5g[lane];
#pragma unroll
    for (int m = 1; m < 64; m <<= 1) qa += __shfl_xor(qa, m);

    f32x4 uf[2][2];
#pragma unroll
    for (int s = 0; s < 2; ++s) {
        uf[s][0] = *(const f32x4*)&uS[s * 32 + quad * 8];
        uf[s][1] = *(const f32x4*)&uS[s * 32 + quad * 8 + 4];
    }

    float res[8];
#pragma unroll
    for (int kt = 0; kt < 8; ++kt) {
        const int row = (kt * 16 + l15) * 64;
        bf16x8 m0 = *(const bf16x8*)&muS[row + ((quad) ^ sw) * 8];
        bf16x8 m1 = *(const bf16x8*)&muS[row + ((4 + quad) ^ sw) * 8];
        float r = 0.f;
#pragma unroll
        for (int j = 0; j < 4; ++j) {
            r = fmaf((float)m0[j],     uf[0][0][j], r);
            r = fmaf((float)m0[4 + j], uf[0][1][j], r);
            r = fmaf((float)m1[j],     uf[1][0][j], r);
            r = fmaf((float)m1[4 + j], uf[1][1][j], r);
        }
        r += __shfl_xor(r, 16); r += __shfl_xor(r, 32);
        res[kt] = r;
    }
    float rA0 = (quad & 1) ? res[1] : res[0];
    float rA1 = (quad & 1) ? res[3] : res[2];
    float rA  = (quad & 2) ? rA1 : rA0;
    float rB0 = (quad & 1) ? res[5] : res[4];
    float rB1 = (quad & 1) ? res[7] : res[6];
    float rB  = (quad & 2) ? rB1 : rB0;
    Outg[b * 128 + lane]      = qa + rA;   // k = lane       (kt = quad)
    Outg[b * 128 + 64 + lane] = qa + rB;   // k = lane + 64  (kt = quad + 4)
}

extern "C" void kernel_launch(void* const* d_in, const int* in_sizes, int n_in,
                              void* d_out, int out_size, void* d_ws, size_t ws_size,
                              hipStream_t stream) {
    (void)n_in; (void)d_ws; (void)ws_size; (void)out_size;
    const int B = in_sizes[0] >> 7;   // 4096
    qnet_kernel<<<B, 64, 0, stream>>>(
        (const float*)d_in[0], (const float*)d_in[1], (const float*)d_in[2],
        (const float*)d_in[3], (const float*)d_in[4], (const float*)d_in[5],
        (const float*)d_in[6], (const float*)d_in[7], (const float*)d_in[8],
        (float*)d_out);
}